// Round 3
// baseline (508.878 us; speedup 1.0000x reference)
//
#include <hip/hip_runtime.h>
#include <hip/hip_bf16.h>
#include <math.h>

#define NH 8
#define HD 32
#define EDIM 256
#define NL 4
#define NP 20
#define NR 4
#define SEQ 1024
#define BATCH 4
#define TOTAL 20197
#define OFF_SCALE 4.0f

#define M_ENC (BATCH * TOTAL)   // 80788
#define M_PAD 80896             // 632 * 128  (padded rows for the MFMA GEMM)
#define KDIM 256

typedef short bf16x8 __attribute__((ext_vector_type(8)));   // 8 bf16 in 4 VGPRs
typedef float f32x4  __attribute__((ext_vector_type(4)));

// ---------------------------------------------------------------------------
// f32 -> bf16 cast (RNE), with zero-fill padding tail.
// n_src and n_dst are element counts, both divisible by 8; valid data is the
// contiguous prefix [0, n_src).
// ---------------------------------------------------------------------------
__global__ __launch_bounds__(256) void cast_f32_bf16_kernel(
    const float* __restrict__ src, unsigned short* __restrict__ dst,
    long n_src, long n_dst)
{
    long i = (long)blockIdx.x * blockDim.x + threadIdx.x;
    long stride = (long)gridDim.x * blockDim.x;
    for (long e = i * 8; e < n_dst; e += stride * 8) {
        unsigned short o[8];
        if (e < n_src) {
            float4 a = *reinterpret_cast<const float4*>(src + e);
            float4 b = *reinterpret_cast<const float4*>(src + e + 4);
            float f[8] = {a.x, a.y, a.z, a.w, b.x, b.y, b.z, b.w};
            #pragma unroll
            for (int j = 0; j < 8; ++j) {
                unsigned u = __float_as_uint(f[j]);
                o[j] = (unsigned short)((u + 0x7fffu + ((u >> 16) & 1u)) >> 16); // RNE
            }
        } else {
            #pragma unroll
            for (int j = 0; j < 8; ++j) o[j] = 0;
        }
        *reinterpret_cast<uint4*>(dst + e) = *reinterpret_cast<const uint4*>(o);
    }
}

// ---------------------------------------------------------------------------
// bf16 MFMA GEMM: C[m][n] = sum_k A[m][k] * W[n][k]   (A @ W^T), f32 out.
// A: (M_PAD, 256) bf16 (padded rows zero), W: (256, 256) bf16 row-major (N,K).
// 128x128 tile, BK=32, 256 threads = 4 waves, each wave a 64x64 quadrant of
// 4x4 16x16x32 fragments. Reg-staged LDS (uint4), single-buffered.
// Fragment layout per m89/m92-verified mapping:
//   A/B input: row|col = lane&15, k = (lane>>4)*8 + j
//   C/D:       col = lane&15,     row = (lane>>4)*4 + reg
// ---------------------------------------------------------------------------
__global__ __launch_bounds__(256) void gemm_mfma_kernel(
    const unsigned short* __restrict__ A,
    const unsigned short* __restrict__ W,
    float* __restrict__ C,
    int M_real)
{
    __shared__ __align__(16) unsigned short As[128 * 32];
    __shared__ __align__(16) unsigned short Ws[128 * 32];

    const int tid  = threadIdx.x;
    const int m0   = blockIdx.x * 128;
    const int n0   = blockIdx.y * 128;
    const int wave = tid >> 6;
    const int lane = tid & 63;
    const int wr   = wave >> 1;     // 0..1 (M quadrant)
    const int wc   = wave & 1;      // 0..1 (N quadrant)
    const int lrow = lane & 15;
    const int kg   = lane >> 4;     // 0..3

    f32x4 acc[4][4] = {};

    const bf16x8* Asv = reinterpret_cast<const bf16x8*>(As);
    const bf16x8* Wsv = reinterpret_cast<const bf16x8*>(Ws);

    for (int k0 = 0; k0 < KDIM; k0 += 32) {
        // ---- stage 128x32 bf16 tiles of A and W into LDS ----
        #pragma unroll
        for (int it = 0; it < 2; ++it) {
            int s   = tid + it * 256;     // 16B slot in [0,512)
            int row = s >> 2;
            int ks  = s & 3;
            const unsigned short* ga = A + (size_t)(m0 + row) * KDIM + k0 + ks * 8;
            const unsigned short* gw = W + (size_t)(n0 + row) * KDIM + k0 + ks * 8;
            uint4 va = *reinterpret_cast<const uint4*>(ga);
            uint4 vw = *reinterpret_cast<const uint4*>(gw);
            *reinterpret_cast<uint4*>(&As[s * 8]) = va;
            *reinterpret_cast<uint4*>(&Ws[s * 8]) = vw;
        }
        __syncthreads();

        // ---- fragments + MFMA ----
        bf16x8 af[4], bfr[4];
        #pragma unroll
        for (int mi = 0; mi < 4; ++mi)
            af[mi] = Asv[(wr * 64 + mi * 16 + lrow) * 4 + kg];
        #pragma unroll
        for (int nj = 0; nj < 4; ++nj)
            bfr[nj] = Wsv[(wc * 64 + nj * 16 + lrow) * 4 + kg];
        #pragma unroll
        for (int mi = 0; mi < 4; ++mi)
            #pragma unroll
            for (int nj = 0; nj < 4; ++nj)
                acc[mi][nj] = __builtin_amdgcn_mfma_f32_16x16x32_bf16(
                    af[mi], bfr[nj], acc[mi][nj], 0, 0, 0);
        __syncthreads();
    }

    // ---- epilogue: C write (f32) ----
    #pragma unroll
    for (int mi = 0; mi < 4; ++mi) {
        #pragma unroll
        for (int nj = 0; nj < 4; ++nj) {
            int row_base = m0 + wr * 64 + mi * 16 + kg * 4;
            int col      = n0 + wc * 64 + nj * 16 + lrow;
            #pragma unroll
            for (int r = 0; r < 4; ++r) {
                int row = row_base + r;
                if (row < M_real)
                    C[(size_t)row * 256 + col] = acc[mi][nj][r];
            }
        }
    }
}

// ---------------------------------------------------------------------------
// Generic f32 GEMM (projections + out proj):  C = A @ W^T + bias
// ---------------------------------------------------------------------------
__global__ __launch_bounds__(256) void gemm_atb_kernel(
    const float* __restrict__ A, const float* __restrict__ W,
    const float* __restrict__ bias, float* __restrict__ C,
    int M, int N, int K)
{
    __shared__ float As[16][64];
    __shared__ float Wt[16][64];

    const int tid = threadIdx.x;
    const int m0 = blockIdx.x * 64;
    const int n0 = blockIdx.y * 64;
    const int tx = tid & 15;
    const int ty = tid >> 4;
    const int lr = tid >> 2;
    const int lk = (tid & 3) << 2;

    const int am = m0 + lr;
    const int wn = n0 + lr;

    float acc[4][4] = {};

    for (int k0 = 0; k0 < K; k0 += 16) {
        float4 av = make_float4(0.f, 0.f, 0.f, 0.f);
        float4 wv = make_float4(0.f, 0.f, 0.f, 0.f);
        if (am < M) av = *reinterpret_cast<const float4*>(&A[(size_t)am * K + k0 + lk]);
        if (wn < N) wv = *reinterpret_cast<const float4*>(&W[(size_t)wn * K + k0 + lk]);
        As[lk + 0][lr] = av.x; As[lk + 1][lr] = av.y;
        As[lk + 2][lr] = av.z; As[lk + 3][lr] = av.w;
        Wt[lk + 0][lr] = wv.x; Wt[lk + 1][lr] = wv.y;
        Wt[lk + 2][lr] = wv.z; Wt[lk + 3][lr] = wv.w;
        __syncthreads();

        #pragma unroll
        for (int k = 0; k < 16; ++k) {
            float a[4], b[4];
            #pragma unroll
            for (int i = 0; i < 4; ++i) a[i] = As[k][ty * 4 + i];
            #pragma unroll
            for (int j = 0; j < 4; ++j) b[j] = Wt[k][tx * 4 + j];
            #pragma unroll
            for (int i = 0; i < 4; ++i)
                #pragma unroll
                for (int j = 0; j < 4; ++j)
                    acc[i][j] += a[i] * b[j];
        }
        __syncthreads();
    }

    #pragma unroll
    for (int i = 0; i < 4; ++i) {
        int m = m0 + ty * 4 + i;
        if (m >= M) continue;
        #pragma unroll
        for (int j = 0; j < 4; ++j) {
            int n = n0 + tx * 4 + j;
            if (n >= N) continue;
            float v = acc[i][j];
            if (bias) v += bias[n];
            C[(size_t)m * N + n] = v;
        }
    }
}

// ---------------------------------------------------------------------------
// Deformable sampling (unchanged from baseline).
// ---------------------------------------------------------------------------
__global__ __launch_bounds__(256) void deform_sample_kernel(
    const float* __restrict__ values,    // (B, TOTAL, NH, HD)
    const float* __restrict__ proj_off,  // (B*SEQ, NH*NL*NP*2)
    const float* __restrict__ proj_attn, // (B*SEQ, NH*NL*NP)
    const float* __restrict__ proj_ref,  // (B*SEQ, NH*NR)
    const float* __restrict__ def_refs,  // (NR, 2)
    float* __restrict__ out)             // (B*SEQ, NH*HD)
{
    const int row = blockIdx.x;
    const int b = row / SEQ;
    const int tid = threadIdx.x;

    __shared__ float attn_sm[NH * NL * NP];
    __shared__ float anchors[NH][2];
    __shared__ int   sidx[NH * NL * NP][4];
    __shared__ float scw[NH * NL * NP][4];

    if (tid < NH) {
        const int h = tid;
        float rv[NR];
        float rmax = -1e30f;
        #pragma unroll
        for (int r = 0; r < NR; ++r) {
            rv[r] = proj_ref[(size_t)row * (NH * NR) + h * NR + r];
            rmax = fmaxf(rmax, rv[r]);
        }
        float rsum = 0.f;
        #pragma unroll
        for (int r = 0; r < NR; ++r) { rv[r] = expf(rv[r] - rmax); rsum += rv[r]; }
        float ax = 0.f, ay = 0.f;
        #pragma unroll
        for (int r = 0; r < NR; ++r) {
            float pr = rv[r] / rsum;
            float sx = 1.f / (1.f + expf(-def_refs[r * 2 + 0]));
            float sy = 1.f / (1.f + expf(-def_refs[r * 2 + 1]));
            ax += pr * sx; ay += pr * sy;
        }
        anchors[h][0] = ax; anchors[h][1] = ay;

        const float* ap = proj_attn + (size_t)row * (NH * NL * NP) + h * (NL * NP);
        float amax = -1e30f;
        for (int i = 0; i < NL * NP; ++i) amax = fmaxf(amax, ap[i]);
        float asum = 0.f;
        for (int i = 0; i < NL * NP; ++i) {
            float e = expf(ap[i] - amax);
            attn_sm[h * NL * NP + i] = e;
            asum += e;
        }
        float inv = 1.f / asum;
        for (int i = 0; i < NL * NP; ++i) attn_sm[h * NL * NP + i] *= inv;
    }
    __syncthreads();

    const int lh[NL]  = {100, 50, 25, 13};
    const int lw[NL]  = {152, 76, 38, 19};
    const int lst[NL] = {0, 15200, 19000, 19950};

    for (int e = tid; e < NH * NL * NP; e += 256) {
        int h = e / (NL * NP);
        int rem = e % (NL * NP);
        int l = rem / NP;
        int p = rem % NP;
        const float* op = proj_off + (size_t)row * (NH * NL * NP * 2)
                          + ((size_t)((h * NL + l) * NP + p)) * 2;
        float offx = tanhf(op[0]);
        float offy = tanhf(op[1]);
        int ww = lw[l], hh = lh[l];
        float locx = anchors[h][0] + offx * (OFF_SCALE / (float)ww);
        float locy = anchors[h][1] + offy * (OFF_SCALE / (float)hh);
        locx = fminf(fmaxf(locx, 0.f), 1.f);
        locy = fminf(fmaxf(locy, 0.f), 1.f);
        float x = locx * (float)ww - 0.5f;
        float y = locy * (float)hh - 0.5f;
        float x0f = floorf(x), y0f = floorf(y);
        int x0 = (int)x0f, y0 = (int)y0f;
        float wx = x - x0f, wy = y - y0f;
        #pragma unroll
        for (int cr = 0; cr < 4; ++cr) {
            int xi = x0 + (cr & 1);
            int yi = y0 + (cr >> 1);
            bool valid = (xi >= 0) && (xi < ww) && (yi >= 0) && (yi < hh);
            sidx[e][cr] = valid ? (lst[l] + yi * ww + xi) : -1;
            float cwx = (cr & 1) ? wx : (1.f - wx);
            float cwy = (cr >> 1) ? wy : (1.f - wy);
            scw[e][cr] = cwx * cwy;
        }
    }
    __syncthreads();

    const int h = tid >> 5;
    const int c = tid & 31;
    const float* vb = values + ((size_t)b * TOTAL * NH + h) * HD + c;
    float acc = 0.f;
    for (int i = 0; i < NL * NP; ++i) {
        int e = h * (NL * NP) + i;
        float wa = attn_sm[e];
        float v = 0.f;
        #pragma unroll
        for (int cr = 0; cr < 4; ++cr) {
            int idx = sidx[e][cr];
            if (idx >= 0) v += scw[e][cr] * vb[(size_t)idx * (NH * HD)];
        }
        acc += wa * v;
    }
    out[(size_t)row * (NH * HD) + h * HD + c] = acc;
}

// ---------------------------------------------------------------------------
extern "C" void kernel_launch(void* const* d_in, const int* in_sizes, int n_in,
                              void* d_out, int out_size, void* d_ws, size_t ws_size,
                              hipStream_t stream)
{
    const float* x        = (const float*)d_in[0];
    const float* enc      = (const float*)d_in[1];
    const float* v_w      = (const float*)d_in[2];
    const float* out_w    = (const float*)d_in[3];
    const float* off_w    = (const float*)d_in[4];
    const float* off_b    = (const float*)d_in[5];
    const float* attn_w   = (const float*)d_in[6];
    const float* attn_b   = (const float*)d_in[7];
    const float* ref_w    = (const float*)d_in[8];
    const float* ref_b    = (const float*)d_in[9];
    const float* def_refs = (const float*)d_in[10];
    float* out = (float*)d_out;

    const int M_Q    = BATCH * SEQ;       // 4096
    const int N_OFF  = NH * NL * NP * 2;  // 1280
    const int N_ATTN = NH * NL * NP;      // 640
    const int N_REF  = NH * NR;           // 32

    // ---- workspace layout (aliased; ~124.3 MB) ----
    // [values f32: 20,681,728] [region2: max(enc_bf16 41.4MB, proj_*+attn_out 36.2MB)] [vw_bf16]
    float* ws = (float*)d_ws;
    float* values = ws;                                   // (M_ENC, 256) f32
    char*  region2 = (char*)(values + (size_t)M_ENC * EDIM);
    unsigned short* enc_bf16 = (unsigned short*)region2;  // (M_PAD, 256) bf16, dead after GEMM1
    float* proj_off  = (float*)region2;                   // (M_Q, 1280) — written after GEMM1
    float* proj_attn = proj_off  + (size_t)M_Q * N_OFF;
    float* proj_ref  = proj_attn + (size_t)M_Q * N_ATTN;
    float* attn_out  = proj_ref  + (size_t)M_Q * N_REF;
    unsigned short* vw_bf16 = (unsigned short*)(region2 + (size_t)M_PAD * KDIM * 2);

    dim3 blk(256);
    auto grid2 = [](int M, int N) { return dim3((M + 63) / 64, (N + 63) / 64); };

    // 1) casts: enc -> bf16 (zero-padded to M_PAD rows), v_w -> bf16
    cast_f32_bf16_kernel<<<dim3(2048), blk, 0, stream>>>(
        enc, enc_bf16, (long)M_ENC * EDIM, (long)M_PAD * KDIM);
    cast_f32_bf16_kernel<<<dim3(64), blk, 0, stream>>>(
        v_w, vw_bf16, (long)EDIM * EDIM, (long)EDIM * EDIM);

    // 2) values = encoder_input @ v_w^T  (bf16 MFMA, f32 out)
    gemm_mfma_kernel<<<dim3(M_PAD / 128, EDIM / 128), blk, 0, stream>>>(
        enc_bf16, vw_bf16, values, M_ENC);

    // 3) query projections (f32, bias fused)
    gemm_atb_kernel<<<grid2(M_Q, N_OFF), blk, 0, stream>>>(
        x, off_w, off_b, proj_off, M_Q, N_OFF, EDIM);
    gemm_atb_kernel<<<grid2(M_Q, N_ATTN), blk, 0, stream>>>(
        x, attn_w, attn_b, proj_attn, M_Q, N_ATTN, EDIM);
    gemm_atb_kernel<<<grid2(M_Q, N_REF), blk, 0, stream>>>(
        x, ref_w, ref_b, proj_ref, M_Q, N_REF, EDIM);

    // 4) deformable sampling
    deform_sample_kernel<<<dim3(M_Q), blk, 0, stream>>>(
        values, proj_off, proj_attn, proj_ref, def_refs, attn_out);

    // 5) out = attn_out @ out_w^T (f32)
    gemm_atb_kernel<<<grid2(M_Q, EDIM), blk, 0, stream>>>(
        attn_out, out_w, nullptr, out, M_Q, EDIM, EDIM);
}

// Round 6
// 319.497 us; speedup vs baseline: 1.5927x; 1.5927x over previous
//
#include <hip/hip_runtime.h>
#include <hip/hip_bf16.h>
#include <math.h>

#define NH 8
#define HD 32
#define EDIM 256
#define NL 4
#define NP 20
#define NR 4
#define SEQ 1024
#define BATCH 4
#define TOTAL 20197
#define OFF_SCALE 4.0f

#define M_ENC (BATCH * TOTAL)   // 80788
#define M_PAD 80896             // 632 * 128
#define KDIM 256

typedef short bf16x8 __attribute__((ext_vector_type(8)));
typedef float f32x4  __attribute__((ext_vector_type(4)));

// ---------------------------------------------------------------------------
// f32 -> bf16 cast (RNE), zero-fill padding tail. n_src/n_dst divisible by 8.
// ---------------------------------------------------------------------------
__global__ __launch_bounds__(256) void cast_f32_bf16_kernel(
    const float* __restrict__ src, unsigned short* __restrict__ dst,
    long n_src, long n_dst)
{
    long i = (long)blockIdx.x * blockDim.x + threadIdx.x;
    long stride = (long)gridDim.x * blockDim.x;
    for (long e = i * 8; e < n_dst; e += stride * 8) {
        unsigned short o[8];
        if (e < n_src) {
            float4 a = *reinterpret_cast<const float4*>(src + e);
            float4 b = *reinterpret_cast<const float4*>(src + e + 4);
            float f[8] = {a.x, a.y, a.z, a.w, b.x, b.y, b.z, b.w};
            #pragma unroll
            for (int j = 0; j < 8; ++j) {
                unsigned u = __float_as_uint(f[j]);
                o[j] = (unsigned short)((u + 0x7fffu + ((u >> 16) & 1u)) >> 16);
            }
        } else {
            #pragma unroll
            for (int j = 0; j < 8; ++j) o[j] = 0;
        }
        *reinterpret_cast<uint4*>(dst + e) = *reinterpret_cast<const uint4*>(o);
    }
}

// ---------------------------------------------------------------------------
// bf16 MFMA GEMM: C[m][n] = sum_k A[m][k]*W[n][k] + bias[n]; f32 out.
// A: (M,256) bf16, W: (N,256) bf16 row-major. M mult of 128 (rows >= M_real
// zero-padded), N mult of 128. 128x128 tile, BK=32, 4 waves.
// ---------------------------------------------------------------------------
__global__ __launch_bounds__(256) void gemm_mfma_kernel(
    const unsigned short* __restrict__ A,
    const unsigned short* __restrict__ W,
    const float* __restrict__ bias,
    float* __restrict__ C,
    int M_real, int N)
{
    __shared__ __align__(16) unsigned short As[128 * 32];
    __shared__ __align__(16) unsigned short Ws[128 * 32];

    const int tid  = threadIdx.x;
    const int m0   = blockIdx.x * 128;
    const int n0   = blockIdx.y * 128;
    const int wave = tid >> 6;
    const int lane = tid & 63;
    const int wr   = wave >> 1;
    const int wc   = wave & 1;
    const int lrow = lane & 15;
    const int kg   = lane >> 4;

    f32x4 acc[4][4] = {};

    const bf16x8* Asv = reinterpret_cast<const bf16x8*>(As);
    const bf16x8* Wsv = reinterpret_cast<const bf16x8*>(Ws);

    for (int k0 = 0; k0 < KDIM; k0 += 32) {
        #pragma unroll
        for (int it = 0; it < 2; ++it) {
            int s   = tid + it * 256;
            int row = s >> 2;
            int ks  = s & 3;
            uint4 va = *reinterpret_cast<const uint4*>(A + (size_t)(m0 + row) * KDIM + k0 + ks * 8);
            uint4 vw = *reinterpret_cast<const uint4*>(W + (size_t)(n0 + row) * KDIM + k0 + ks * 8);
            *reinterpret_cast<uint4*>(&As[s * 8]) = va;
            *reinterpret_cast<uint4*>(&Ws[s * 8]) = vw;
        }
        __syncthreads();

        bf16x8 af[4], bfr[4];
        #pragma unroll
        for (int mi = 0; mi < 4; ++mi)
            af[mi] = Asv[(wr * 64 + mi * 16 + lrow) * 4 + kg];
        #pragma unroll
        for (int nj = 0; nj < 4; ++nj)
            bfr[nj] = Wsv[(wc * 64 + nj * 16 + lrow) * 4 + kg];
        #pragma unroll
        for (int mi = 0; mi < 4; ++mi)
            #pragma unroll
            for (int nj = 0; nj < 4; ++nj)
                acc[mi][nj] = __builtin_amdgcn_mfma_f32_16x16x32_bf16(
                    af[mi], bfr[nj], acc[mi][nj], 0, 0, 0);
        __syncthreads();
    }

    #pragma unroll
    for (int mi = 0; mi < 4; ++mi) {
        #pragma unroll
        for (int nj = 0; nj < 4; ++nj) {
            int row_base = m0 + wr * 64 + mi * 16 + kg * 4;
            int col      = n0 + wc * 64 + nj * 16 + lrow;
            float bv = bias ? bias[col] : 0.f;
            #pragma unroll
            for (int r = 0; r < 4; ++r) {
                int row = row_base + r;
                if (row < M_real)
                    C[(size_t)row * N + col] = acc[mi][nj][r] + bv;
            }
        }
    }
}

// ---------------------------------------------------------------------------
// Generic f32 GEMM (ref proj + out proj): C = A @ W^T + bias
// ---------------------------------------------------------------------------
__global__ __launch_bounds__(256) void gemm_atb_kernel(
    const float* __restrict__ A, const float* __restrict__ W,
    const float* __restrict__ bias, float* __restrict__ C,
    int M, int N, int K)
{
    __shared__ float As[16][64];
    __shared__ float Wt[16][64];

    const int tid = threadIdx.x;
    const int m0 = blockIdx.x * 64;
    const int n0 = blockIdx.y * 64;
    const int tx = tid & 15;
    const int ty = tid >> 4;
    const int lr = tid >> 2;
    const int lk = (tid & 3) << 2;

    const int am = m0 + lr;
    const int wn = n0 + lr;

    float acc[4][4] = {};

    for (int k0 = 0; k0 < K; k0 += 16) {
        float4 av = make_float4(0.f, 0.f, 0.f, 0.f);
        float4 wv = make_float4(0.f, 0.f, 0.f, 0.f);
        if (am < M) av = *reinterpret_cast<const float4*>(&A[(size_t)am * K + k0 + lk]);
        if (wn < N) wv = *reinterpret_cast<const float4*>(&W[(size_t)wn * K + k0 + lk]);
        As[lk + 0][lr] = av.x; As[lk + 1][lr] = av.y;
        As[lk + 2][lr] = av.z; As[lk + 3][lr] = av.w;
        Wt[lk + 0][lr] = wv.x; Wt[lk + 1][lr] = wv.y;
        Wt[lk + 2][lr] = wv.z; Wt[lk + 3][lr] = wv.w;
        __syncthreads();

        #pragma unroll
        for (int k = 0; k < 16; ++k) {
            float a[4], b[4];
            #pragma unroll
            for (int i = 0; i < 4; ++i) a[i] = As[k][ty * 4 + i];
            #pragma unroll
            for (int j = 0; j < 4; ++j) b[j] = Wt[k][tx * 4 + j];
            #pragma unroll
            for (int i = 0; i < 4; ++i)
                #pragma unroll
                for (int j = 0; j < 4; ++j)
                    acc[i][j] += a[i] * b[j];
        }
        __syncthreads();
    }

    #pragma unroll
    for (int i = 0; i < 4; ++i) {
        int m = m0 + ty * 4 + i;
        if (m >= M) continue;
        #pragma unroll
        for (int j = 0; j < 4; ++j) {
            int n = n0 + tx * 4 + j;
            if (n >= N) continue;
            float v = acc[i][j];
            if (bias) v += bias[n];
            C[(size_t)m * N + n] = v;
        }
    }
}

// ---------------------------------------------------------------------------
// Deformable sampling, wave-parallel version. One block per query row.
//  Phase A: 160 threads vector-load attn logits -> LDS; 8 threads do the
//           tiny R=4 ref-softmax anchors (concurrent, different waves).
//  Phase A2: per-head softmax, 32-lane group per head, shfl_xor reduce.
//  Phase B: 640 samples: tanh offsets -> clamped u16 corner indices + corner
//           weights with attn weight and validity FOLDED IN (branch-free).
//  Phase C: thread (h,c): 80 samples x 4 unconditional coalesced gathers.
// ---------------------------------------------------------------------------
__global__ __launch_bounds__(256) void deform_sample_kernel(
    const float* __restrict__ values,    // (B, TOTAL, NH, HD)
    const float* __restrict__ proj_off,  // (B*SEQ, 1280)
    const float* __restrict__ proj_attn, // (B*SEQ, 640)
    const float* __restrict__ proj_ref,  // (B*SEQ, 32)
    const float* __restrict__ def_refs,  // (NR, 2)
    float* __restrict__ out)             // (B*SEQ, 256)
{
    const int row = blockIdx.x;
    const int b   = row >> 10;           // SEQ = 1024
    const int tid = threadIdx.x;

    __shared__ float  attn_s[NH * NL * NP];   // 640 f32
    __shared__ float  anchors[NH][2];
    __shared__ unsigned int sidx[NH * NL * NP][2];  // 4 x u16 packed
    __shared__ float4 wcor[NH * NL * NP];           // 4 corner weights

    // ---- Phase A ----
    if (tid >= 96) {            // 160 threads: vector-load attn logits
        int i = tid - 96;
        reinterpret_cast<float4*>(attn_s)[i] =
            reinterpret_cast<const float4*>(proj_attn + (size_t)row * 640)[i];
    } else if (tid < NH) {      // 8 threads: anchors
        const int h = tid;
        float rv[NR];
        float rmax = -1e30f;
        #pragma unroll
        for (int r = 0; r < NR; ++r) {
            rv[r] = proj_ref[(size_t)row * (NH * NR) + h * NR + r];
            rmax = fmaxf(rmax, rv[r]);
        }
        float rsum = 0.f;
        #pragma unroll
        for (int r = 0; r < NR; ++r) { rv[r] = __expf(rv[r] - rmax); rsum += rv[r]; }
        float ax = 0.f, ay = 0.f;
        #pragma unroll
        for (int r = 0; r < NR; ++r) {
            float pr = rv[r] / rsum;
            float sx = 1.f / (1.f + __expf(-def_refs[r * 2 + 0]));
            float sy = 1.f / (1.f + __expf(-def_refs[r * 2 + 1]));
            ax += pr * sx; ay += pr * sy;
        }
        anchors[h][0] = ax; anchors[h][1] = ay;
    }
    __syncthreads();

    // ---- Phase A2: per-head softmax over 80, 32 lanes per head ----
    {
        const int g = tid >> 5;   // head
        const int l = tid & 31;
        float v0 = attn_s[g * 80 + l];
        float v1 = attn_s[g * 80 + 32 + l];
        float v2 = (l < 16) ? attn_s[g * 80 + 64 + l] : -1e30f;
        float m = fmaxf(fmaxf(v0, v1), v2);
        #pragma unroll
        for (int d = 16; d >= 1; d >>= 1) m = fmaxf(m, __shfl_xor(m, d, 64));
        float e0 = __expf(v0 - m), e1 = __expf(v1 - m);
        float e2 = (l < 16) ? __expf(v2 - m) : 0.f;
        float s = e0 + e1 + e2;
        #pragma unroll
        for (int d = 16; d >= 1; d >>= 1) s += __shfl_xor(s, d, 64);
        float inv = 1.f / s;
        __syncthreads();   // all reads of raw logits done before overwrite
        attn_s[g * 80 + l]      = e0 * inv;
        attn_s[g * 80 + 32 + l] = e1 * inv;
        if (l < 16) attn_s[g * 80 + 64 + l] = e2 * inv;
    }
    __syncthreads();

    // ---- Phase B: sample locations -> packed indices + folded weights ----
    const int lhh[NL] = {100, 50, 25, 13};
    const int lww[NL] = {152, 76, 38, 19};
    const int lst[NL] = {0, 15200, 19000, 19950};

    for (int e = tid; e < NH * NL * NP; e += 256) {
        int h = e / 80;
        int rem = e - h * 80;
        int l = rem / 20;
        const float2 o = *reinterpret_cast<const float2*>(
            proj_off + (size_t)row * 1280 + e * 2);
        float offx = tanhf(o.x);
        float offy = tanhf(o.y);
        int ww = lww[l], hh = lhh[l];
        float locx = fminf(fmaxf(anchors[h][0] + offx * (OFF_SCALE / (float)ww), 0.f), 1.f);
        float locy = fminf(fmaxf(anchors[h][1] + offy * (OFF_SCALE / (float)hh), 0.f), 1.f);
        float xx = locx * (float)ww - 0.5f;
        float yy = locy * (float)hh - 0.5f;
        float x0f = floorf(xx), y0f = floorf(yy);
        int x0 = (int)x0f, y0 = (int)y0f;    // x0 in [-1, ww-1], y0 in [-1, hh-1]
        float wx = xx - x0f, wy = yy - y0f;
        float wa = attn_s[e];

        float bx0 = (x0 >= 0)      ? 1.f : 0.f;
        float bx1 = (x0 < ww - 1)  ? 1.f : 0.f;
        float by0 = (y0 >= 0)      ? 1.f : 0.f;
        float by1 = (y0 < hh - 1)  ? 1.f : 0.f;
        int xc0 = max(x0, 0), xc1 = min(x0 + 1, ww - 1);
        int yc0 = max(y0, 0), yc1 = min(y0 + 1, hh - 1);
        unsigned int i00 = (unsigned int)(lst[l] + yc0 * ww + xc0);
        unsigned int i10 = (unsigned int)(lst[l] + yc0 * ww + xc1);
        unsigned int i01 = (unsigned int)(lst[l] + yc1 * ww + xc0);
        unsigned int i11 = (unsigned int)(lst[l] + yc1 * ww + xc1);

        float4 w;
        w.x = wa * (1.f - wx) * (1.f - wy) * bx0 * by0;
        w.y = wa * wx * (1.f - wy) * bx1 * by0;
        w.z = wa * (1.f - wx) * wy * bx0 * by1;
        w.w = wa * wx * wy * bx1 * by1;

        sidx[e][0] = i00 | (i10 << 16);
        sidx[e][1] = i01 | (i11 << 16);
        wcor[e] = w;
    }
    __syncthreads();

    // ---- Phase C: gather + accumulate ----
    const int h = tid >> 5;
    const int c = tid & 31;
    const float* vb = values + (size_t)b * TOTAL * 256 + h * 32 + c;
    float acc = 0.f;
    #pragma unroll 4
    for (int i = 0; i < 80; ++i) {
        int e = h * 80 + i;
        unsigned int p0 = sidx[e][0];
        unsigned int p1 = sidx[e][1];
        float4 w = wcor[e];
        float v00 = vb[(size_t)(p0 & 0xffffu) * 256];
        float v10 = vb[(size_t)(p0 >> 16) * 256];
        float v01 = vb[(size_t)(p1 & 0xffffu) * 256];
        float v11 = vb[(size_t)(p1 >> 16) * 256];
        acc += w.x * v00 + w.y * v10 + w.z * v01 + w.w * v11;
    }
    out[(size_t)row * 256 + h * 32 + c] = acc;
}

// ---------------------------------------------------------------------------
extern "C" void kernel_launch(void* const* d_in, const int* in_sizes, int n_in,
                              void* d_out, int out_size, void* d_ws, size_t ws_size,
                              hipStream_t stream)
{
    const float* x        = (const float*)d_in[0];
    const float* enc      = (const float*)d_in[1];
    const float* v_w      = (const float*)d_in[2];
    const float* out_w    = (const float*)d_in[3];
    const float* off_w    = (const float*)d_in[4];
    const float* off_b    = (const float*)d_in[5];
    const float* attn_w   = (const float*)d_in[6];
    const float* attn_b   = (const float*)d_in[7];
    const float* ref_w    = (const float*)d_in[8];
    const float* ref_b    = (const float*)d_in[9];
    const float* def_refs = (const float*)d_in[10];
    float* out = (float*)d_out;

    const int M_Q    = BATCH * SEQ;       // 4096
    const int N_OFF  = NH * NL * NP * 2;  // 1280
    const int N_ATTN = NH * NL * NP;      // 640
    const int N_REF  = NH * NR;           // 32

    // ---- workspace layout (~124.3 MB, same as round 2) ----
    // [values f32 82.73MB][region2 41.42MB][vw_bf16 128KB]
    // region2 holds enc_bf16 (dead after values GEMM), then is reused for:
    //   proj_off(21.0) proj_attn(10.5) proj_ref(0.5) attn_out(4.2) = 36.2MB
    //   + x_bf16(2.0) offw_bf16(0.65) attnw_bf16(0.33) at 36.2..39.2MB
    float* ws = (float*)d_ws;
    float* values = ws;
    char*  region2 = (char*)(values + (size_t)M_ENC * EDIM);
    unsigned short* enc_bf16 = (unsigned short*)region2;
    float* proj_off  = (float*)region2;
    float* proj_attn = proj_off  + (size_t)M_Q * N_OFF;
    float* proj_ref  = proj_attn + (size_t)M_Q * N_ATTN;
    float* attn_out  = proj_ref  + (size_t)M_Q * N_REF;
    unsigned short* x_bf16     = (unsigned short*)(attn_out + (size_t)M_Q * EDIM);
    unsigned short* offw_bf16  = x_bf16 + (size_t)M_Q * KDIM;
    unsigned short* attnw_bf16 = offw_bf16 + (size_t)N_OFF * KDIM;
    unsigned short* vw_bf16    = (unsigned short*)(region2 + (size_t)M_PAD * KDIM * 2);

    dim3 blk(256);

    // 1) casts for the values GEMM
    cast_f32_bf16_kernel<<<dim3(2048), blk, 0, stream>>>(
        enc, enc_bf16, (long)M_ENC * EDIM, (long)M_PAD * KDIM);
    cast_f32_bf16_kernel<<<dim3(64), blk, 0, stream>>>(
        v_w, vw_bf16, (long)EDIM * EDIM, (long)EDIM * EDIM);

    // 2) values = enc @ v_w^T (bf16 MFMA) — must finish before region2 reuse
    gemm_mfma_kernel<<<dim3(M_PAD / 128, EDIM / 128), blk, 0, stream>>>(
        enc_bf16, vw_bf16, nullptr, values, M_ENC, EDIM);

    // 3) casts for projection GEMMs (overwrite dead enc_bf16 tail)
    cast_f32_bf16_kernel<<<dim3(512), blk, 0, stream>>>(
        x, x_bf16, (long)M_Q * EDIM, (long)M_Q * EDIM);
    cast_f32_bf16_kernel<<<dim3(160), blk, 0, stream>>>(
        off_w, offw_bf16, (long)N_OFF * EDIM, (long)N_OFF * EDIM);
    cast_f32_bf16_kernel<<<dim3(40), blk, 0, stream>>>(
        attn_w, attnw_bf16, (long)N_ATTN * EDIM, (long)N_ATTN * EDIM);

    // 4) projections: off + attn via MFMA (bias fused), ref via f32
    gemm_mfma_kernel<<<dim3(M_Q / 128, N_OFF / 128), blk, 0, stream>>>(
        x_bf16, offw_bf16, off_b, proj_off, M_Q, N_OFF);
    gemm_mfma_kernel<<<dim3(M_Q / 128, N_ATTN / 128), blk, 0, stream>>>(
        x_bf16, attnw_bf16, attn_b, proj_attn, M_Q, N_ATTN);
    gemm_atb_kernel<<<dim3(M_Q / 64, 1), blk, 0, stream>>>(
        x, ref_w, ref_b, proj_ref, M_Q, N_REF, EDIM);

    // 5) deformable sampling (wave-parallel)
    deform_sample_kernel<<<dim3(M_Q), blk, 0, stream>>>(
        values, proj_off, proj_attn, proj_ref, def_refs, attn_out);

    // 6) out = attn_out @ out_w^T (f32)
    gemm_atb_kernel<<<dim3(M_Q / 64, EDIM / 64), blk, 0, stream>>>(
        attn_out, out_w, nullptr, out, M_Q, EDIM, EDIM);
}